// Round 7
// baseline (896.535 us; speedup 1.0000x reference)
//
#include <hip/hip_runtime.h>

typedef unsigned short ushort_t;
typedef __attribute__((ext_vector_type(8))) short short8;
typedef __attribute__((ext_vector_type(8))) unsigned short ushort8;
typedef __attribute__((ext_vector_type(4))) float floatx4;

#define M_TOT 32768   // B*S
#define KDIM  1024    // folded reduction dim (x part only)
#define N2    4096    // 2 * 2048 (q,k outputs only; v eliminated via Wpv folding)
#define D2    2048
#define NBATCH 1024
#define SSEQ   32

__device__ __forceinline__ ushort_t f2bf(float f){
  unsigned int u = __builtin_bit_cast(unsigned int, f);
  u += 0x7fffu + ((u >> 16) & 1u);           // RNE
  return (ushort_t)(u >> 16);
}

__device__ __forceinline__ void gld16(const void* g, void* l){
  __builtin_amdgcn_global_load_lds((__attribute__((address_space(1))) void*)g,
                                   (__attribute__((address_space(3))) void*)l,
                                   16, 0, 0);
}

__device__ __forceinline__ void barrier_raw(){
  asm volatile("" ::: "memory");
  __builtin_amdgcn_s_barrier();
  asm volatile("" ::: "memory");
}
#define WAIT_VM(N)  asm volatile("s_waitcnt vmcnt(" #N ")" ::: "memory")
#define WAIT_LGKM0  asm volatile("s_waitcnt lgkmcnt(0)" ::: "memory")

// ---------------- prep kernels ----------------

__global__ void k_cast_x(const float* __restrict__ x, ushort_t* __restrict__ xb){
  size_t i = (size_t)blockIdx.x * 256 + threadIdx.x;   // one thread per 8 elems
  const float4* s = (const float4*)x;
  float4 a = s[2*i], b = s[2*i+1];
  ushort8 o;
  o[0]=f2bf(a.x); o[1]=f2bf(a.y); o[2]=f2bf(a.z); o[3]=f2bf(a.w);
  o[4]=f2bf(b.x); o[5]=f2bf(b.y); o[6]=f2bf(b.z); o[7]=f2bf(b.w);
  *(ushort8*)(xb + 8*i) = o;
}

// W_all[row=p*2048+n][j] = W_p[n][j] for j<1024, p in {q,k}
__global__ void k_cast_w(const float* __restrict__ Wq, const float* __restrict__ Wk,
                         ushort_t* __restrict__ Wall){
  int i = blockIdx.x * 256 + threadIdx.x;
  int e = i * 8;
  int row = e >> 10, col = e & 1023;
  int p = row >> 11, n = row & 2047;
  const float* W = (p==0) ? Wq : Wk;
  const float4* s = (const float4*)(W + (size_t)n*2048 + col);
  float4 a = s[0], b = s[1];
  ushort8 o;
  o[0]=f2bf(a.x); o[1]=f2bf(a.y); o[2]=f2bf(a.z); o[3]=f2bf(a.w);
  o[4]=f2bf(b.x); o[5]=f2bf(b.y); o[6]=f2bf(b.z); o[7]=f2bf(b.w);
  *(ushort8*)(Wall + (size_t)row*1024 + col) = o;
}

// bias_all[s][p*2048+n] = b_p[n] + sum_j pe[s][j] * W_p[n][1024+j]   (fp32), p in {q,k}
__global__ void k_bias(const float* __restrict__ pe,
                       const float* __restrict__ Wq, const float* __restrict__ bq,
                       const float* __restrict__ Wk, const float* __restrict__ bk,
                       float* __restrict__ bias_all){
  int t = threadIdx.x;
  int ni = t & 7, s = t >> 3;
  int col = blockIdx.x * 8 + ni;           // 0..4095
  int p = col >> 11, n = col & 2047;
  const float* W  = (p==0) ? Wq : Wk;
  const float* bb = (p==0) ? bq : bk;
  const float4* w4 = (const float4*)(W + (size_t)n*2048 + 1024);
  const float4* p4 = (const float4*)(pe + (size_t)s*1024);
  float acc = 0.f;
  #pragma unroll 4
  for (int j = 0; j < 256; ++j){
    float4 w = w4[j], q = p4[j];
    acc += w.x*q.x + w.y*q.y + w.z*q.z + w.w*q.w;
  }
  bias_all[(size_t)s*N2 + col] = acc + bb[n];
}

// Wpv[qi][j] = sum_d Wfc[qi*2048+d] * Wv[d][j]  (fp32; left half also cast to bf16)
// grid 32 (j-tiles of 64), 256 threads: j = t&63, qg = t>>6 (8 qi per thread)
__global__ void k_wpv(const float* __restrict__ Wv, const float* __restrict__ Wfc,
                      float* __restrict__ Wpv, ushort_t* __restrict__ Wpvb){
  int j = blockIdx.x * 64 + (threadIdx.x & 63);
  int qg = threadIdx.x >> 6;
  float acc[8] = {};
  #pragma unroll 4
  for (int d = 0; d < 2048; ++d){
    float wv = Wv[(size_t)d*2048 + j];
    #pragma unroll
    for (int u = 0; u < 8; ++u)
      acc[u] += wv * Wfc[(size_t)(qg*8+u)*2048 + d];
  }
  #pragma unroll
  for (int u = 0; u < 8; ++u){
    int qi = qg*8 + u;
    Wpv[(size_t)qi*2048 + j] = acc[u];
    if (j < 1024) Wpvb[(size_t)qi*1024 + j] = f2bf(acc[u]);
  }
}

// biasp[s][qi] = sum_{j'} pe[s][j'] * Wpv[qi][1024+j'] + sum_d bv[d]*Wfc[qi*2048+d]
__global__ void k_biasp(const float* __restrict__ pe, const float* __restrict__ Wpv,
                        const float* __restrict__ bv, const float* __restrict__ Wfc,
                        float* __restrict__ biasp){
  int idx = blockIdx.x * 256 + threadIdx.x;   // 0..1023
  int s = idx >> 5, qi = idx & 31;
  const float4* p4 = (const float4*)(pe + (size_t)s*1024);
  const float4* w4 = (const float4*)(Wpv + (size_t)qi*2048 + 1024);
  float acc = 0.f;
  #pragma unroll 4
  for (int jj = 0; jj < 256; ++jj){
    float4 a = p4[jj], b = w4[jj];
    acc += a.x*b.x + a.y*b.y + a.z*b.z + a.w*b.w;
  }
  const float4* b4 = (const float4*)bv;
  const float4* f4 = (const float4*)(Wfc + (size_t)qi*2048);
  #pragma unroll 4
  for (int dd = 0; dd < 512; ++dd){
    float4 a = b4[dd], b = f4[dd];
    acc += a.x*b.x + a.y*b.y + a.z*b.z + a.w*b.w;
  }
  biasp[(size_t)s*32 + qi] = acc;
}

// ---------------- QK GEMM: 256x256 tile, BK=64, 8 waves (2x4), m201-style 8-phase ----------------
// (r4/r6 kernel verbatim, N3 -> N2; verified: 0 bank conflicts, MfmaUtil 37.6%)
__global__ __launch_bounds__(512, 1) void k_gemm(const ushort_t* __restrict__ xb,
                                                 const ushort_t* __restrict__ Wall,
                                                 const float* __restrict__ bias_all,
                                                 ushort_t* __restrict__ qkv){
  __shared__ alignas(16) ushort_t sA[2][2*128*64];   // [dbuf][half*8192 + r*64 + c*8]
  __shared__ alignas(16) ushort_t sB[2][2*128*64];

  const int t = threadIdx.x, w = t >> 6, l = t & 63;
  const int wr = w >> 2, wc = w & 3;          // 2x4 wave grid -> wave owns 128x64 of C
  const int lr = l & 15, lg = l >> 4;
  const int m0 = blockIdx.x * 256;
  const int n0 = blockIdx.y * 256;

  const ushort_t* gA = xb   + (size_t)m0 * KDIM;
  const ushort_t* gB = Wall + (size_t)n0 * KDIM;

  floatx4 acc[8][4] = {};   // [mh*4+mi][nh*2+ni]

  auto STAGE_A = [&](int kt, int d, int h){
    #pragma unroll
    for (int j = 0; j < 2; ++j){
      int p = j*512 + t;
      int wr_ = p >> 9, ridx = (p >> 3) & 63, c = (p & 7) ^ (ridx & 7);
      int R = wr_*128 + h*64 + ridx;
      gld16(gA + (size_t)R*KDIM + kt*64 + c*8, &sA[d][(size_t)h*8192 + (size_t)(j*512 + w*64)*8]);
    }
  };
  auto STAGE_B = [&](int kt, int d, int h){
    #pragma unroll
    for (int j = 0; j < 2; ++j){
      int p = j*512 + t;
      int wc_ = p >> 8, ridx = (p >> 3) & 31, c = (p & 7) ^ (ridx & 7);
      int R = wc_*64 + h*32 + ridx;
      gld16(gB + (size_t)R*KDIM + kt*64 + c*8, &sB[d][(size_t)h*8192 + (size_t)(j*512 + w*64)*8]);
    }
  };

  short8 a[8], b0[4], b1[4];
  auto RDA = [&](int d, int mh){      // 8 ds_read_b128
    #pragma unroll
    for (int mi = 0; mi < 4; ++mi)
      #pragma unroll
      for (int ks = 0; ks < 2; ++ks){
        int ch = (ks*4 + lg) ^ (lr & 7);
        a[mi*2+ks] = *(const short8*)&sA[d][(size_t)mh*8192 + (size_t)(wr*64 + mi*16 + lr)*64 + ch*8];
      }
  };
  auto RDB = [&](int d, int nh, short8* b){   // 4 ds_read_b128
    #pragma unroll
    for (int ni = 0; ni < 2; ++ni)
      #pragma unroll
      for (int ks = 0; ks < 2; ++ks){
        int ch = (ks*4 + lg) ^ (lr & 7);
        b[ni*2+ks] = *(const short8*)&sB[d][(size_t)nh*8192 + (size_t)(wc*32 + ni*16 + lr)*64 + ch*8];
      }
  };
  auto MM = [&](int mh, int nh, const short8* b){   // 16 MFMA (one quadrant x K=64)
    #pragma unroll
    for (int mi = 0; mi < 4; ++mi)
      #pragma unroll
      for (int ni = 0; ni < 2; ++ni)
        #pragma unroll
        for (int ks = 0; ks < 2; ++ks)
          acc[mh*4+mi][nh*2+ni] = __builtin_amdgcn_mfma_f32_16x16x32_bf16(
              a[mi*2+ks], b[ni*2+ks], acc[mh*4+mi][nh*2+ni], 0, 0, 0);
  };

  #define MIDBAR  do { barrier_raw(); WAIT_LGKM0; __builtin_amdgcn_sched_barrier(0); } while(0)
  #define PRIO_MM(mh, nh, b) do { __builtin_amdgcn_s_setprio(1); MM(mh, nh, b); __builtin_amdgcn_s_setprio(0); } while(0)

  // prologue: tau0 (all 4 halves) + tau1 {A.h0, B.h1}; drain to last-4; barrier
  STAGE_A(0,0,0); STAGE_B(0,0,1); STAGE_A(0,0,1); STAGE_B(0,0,0);
  STAGE_A(1,1,0); STAGE_B(1,1,1);
  WAIT_VM(4);
  barrier_raw();

  const int NI = KDIM / 128;   // 8 iters, 2 K-tiles each
  for (int i = 0; i < NI; ++i){
    const int t1 = 2*i+1, t2 = 2*i+2, t3 = 2*i+3;
    const bool pre = (i < NI-1);

    // P1: Q(mh0,nh0) of tau0; stage tau1 {A.h1, B.h0} -> dbuf1
    RDA(0,0); RDB(0,0,b0);
    STAGE_A(t1,1,1); STAGE_B(t1,1,0);
    MIDBAR; PRIO_MM(0,0,b0);
    barrier_raw();
    // P2
    RDB(0,1,b1);
    MIDBAR; PRIO_MM(0,1,b1);
    barrier_raw();
    // P3
    RDA(0,1);
    if (pre) STAGE_A(t2,0,0);
    MIDBAR; PRIO_MM(1,1,b1);
    barrier_raw();
    // P4
    if (pre) STAGE_B(t2,0,1);
    MIDBAR; PRIO_MM(1,0,b0);
    if (pre) { WAIT_VM(4); } else { WAIT_VM(0); }
    barrier_raw();

    // P5
    RDA(1,0); RDB(1,0,b0);
    if (pre){ STAGE_A(t2,0,1); STAGE_B(t2,0,0); }
    MIDBAR; PRIO_MM(0,0,b0);
    barrier_raw();
    // P6
    RDB(1,1,b1);
    MIDBAR; PRIO_MM(0,1,b1);
    barrier_raw();
    // P7
    RDA(1,1);
    if (pre) STAGE_A(t3,1,0);
    MIDBAR; PRIO_MM(1,1,b1);
    barrier_raw();
    // P8
    if (pre) STAGE_B(t3,1,1);
    MIDBAR; PRIO_MM(1,0,b0);
    if (pre) { WAIT_VM(4); }
    barrier_raw();
  }

  // epilogue: C/D layout col=lr, row=lg*4+r
  #pragma unroll
  for (int mh = 0; mh < 2; ++mh)
    #pragma unroll
    for (int mi = 0; mi < 4; ++mi)
      #pragma unroll
      for (int nh = 0; nh < 2; ++nh)
        #pragma unroll
        for (int ni = 0; ni < 2; ++ni)
          #pragma unroll
          for (int r = 0; r < 4; ++r){
            int row = m0 + wr*128 + mh*64 + mi*16 + lg*4 + r;
            int col = n0 + wc*64 + nh*32 + ni*16 + lr;
            float v = acc[mh*4+mi][nh*2+ni][r] + bias_all[(size_t)(row & 31)*N2 + col];
            qkv[(size_t)row*N2 + col] = f2bf(v);
          }
  #undef MIDBAR
  #undef PRIO_MM
}

// ---------------- fused attention tail ----------------
// phase A: logits = q k^T / sqrt(2048) over 2048 dims (pipelined slices)
// softmax over query axis; phase B: P[ki][qi] = x_b @ Wpv^T + biasp; out = sum attn*P + bfc
__global__ __launch_bounds__(256) void k_attn(const ushort_t* __restrict__ qkv,
                                              const ushort_t* __restrict__ xb,
                                              const ushort_t* __restrict__ Wpvb,
                                              const float* __restrict__ biasp,
                                              const float* __restrict__ bfc,
                                              float* __restrict__ out){
  __shared__ alignas(16) ushort_t s0[2][32*64];   // q / x
  __shared__ alignas(16) ushort_t s1[2][32*64];   // k / Wpv
  __shared__ float attn[32*32];
  __shared__ float red[4];
  const int b = blockIdx.x;
  const int t = threadIdx.x, w = t >> 6, l = t & 63;
  const int qh = w >> 1, kh = w & 1;
  const int lr = l & 15, lg = l >> 4;

  const int srow = t >> 3;
  const int scol = ((t & 7) ^ (srow & 7)) * 8;
  const ushort_t* baseq = qkv + (size_t)(b*32)*N2;
  const ushort_t* gq = baseq + (size_t)srow*N2 + scol;
  const ushort_t* gx = xb + (size_t)(b*32 + srow)*KDIM + scol;
  const ushort_t* gp = Wpvb + (size_t)srow*KDIM + scol;

  auto STAGE_QK = [&](int s){
    const int d = s & 1;
    gld16(gq + s*64,      &s0[d][(w*64)*8]);
    gld16(gq + D2 + s*64, &s1[d][(w*64)*8]);
  };
  auto STAGE_XP = [&](int s){
    const int d = s & 1;
    gld16(gx + s*64, &s0[d][(w*64)*8]);
    gld16(gp + s*64, &s1[d][(w*64)*8]);
  };
  auto RD = [&](const ushort_t* s_, int row, int kc) -> short8 {
    int ch = (kc*4 + lg) ^ (row & 7);
    return *(const short8*)(s_ + (size_t)(row*8 + ch)*8);
  };

  const int rowq = qh*16 + lr, rowk = kh*16 + lr;
  floatx4 aq = {0.f, 0.f, 0.f, 0.f};

  // ---- phase A: logits over 2048 dims, 32 slices of 64 ----
  STAGE_QK(0); STAGE_QK(1);            // 4 loads in flight
  const int NSA = D2 / 64;
  for (int s = 0; s < NSA; ++s){
    const int d = s & 1;
    if (s == NSA-1) { WAIT_VM(0); } else { WAIT_VM(2); }
    barrier_raw();
    #pragma unroll
    for (int kc = 0; kc < 2; ++kc){
      short8 vq = RD(s0[d], rowq, kc);
      short8 vk = RD(s1[d], rowk, kc);
      aq = __builtin_amdgcn_mfma_f32_16x16x32_bf16(vq, vk, aq, 0, 0, 0);
    }
    WAIT_LGKM0;
    barrier_raw();
    if (s + 2 < NSA) STAGE_QK(s + 2);
  }

  // prefetch phase B slices under the softmax
  STAGE_XP(0); STAGE_XP(1);

  const float rs = 0.022097086912079608f;  // 1/sqrt(2048)
  #pragma unroll
  for (int r = 0; r < 4; ++r){
    int qi = qh*16 + lg*4 + r, ki = kh*16 + lr;
    attn[qi*32 + ki] = aq[r] * rs;
  }
  __syncthreads();

  // softmax over query axis (column-wise), t<32 handles column ki=t
  if (t < 32){
    int ki = t;
    float mx = -1e30f;
    #pragma unroll 4
    for (int qi = 0; qi < 32; ++qi) mx = fmaxf(mx, attn[qi*32 + ki]);
    float sm = 0.f;
    #pragma unroll 4
    for (int qi = 0; qi < 32; ++qi){
      float e = __expf(attn[qi*32 + ki] - mx);
      attn[qi*32 + ki] = e; sm += e;
    }
    float inv = 1.0f / sm;
    #pragma unroll 4
    for (int qi = 0; qi < 32; ++qi) attn[qi*32 + ki] *= inv;
  }
  __syncthreads();

  // ---- phase B: P = x_b @ Wpv^T over 1024 dims, 16 slices ----
  floatx4 ap = {0.f, 0.f, 0.f, 0.f};
  const int NSB = KDIM / 64;
  for (int s = 0; s < NSB; ++s){
    const int d = s & 1;
    if (s == NSB-1) { WAIT_VM(0); } else { WAIT_VM(2); }
    barrier_raw();
    #pragma unroll
    for (int kc = 0; kc < 2; ++kc){
      short8 vx = RD(s0[d], rowk, kc);   // A = x rows (ki side)
      short8 vp = RD(s1[d], rowq, kc);   // B = Wpv rows (qi side)
      ap = __builtin_amdgcn_mfma_f32_16x16x32_bf16(vx, vp, ap, 0, 0, 0);
    }
    WAIT_LGKM0;
    barrier_raw();
    if (s + 2 < NSB) STAGE_XP(s + 2);
  }

  // ap[r]: row=ki=kh*16+lg*4+r, col=qi=qh*16+lr
  float sum = 0.f;
  #pragma unroll
  for (int r = 0; r < 4; ++r){
    int ki = kh*16 + lg*4 + r, qi = qh*16 + lr;
    sum += (ap[r] + biasp[ki*32 + qi]) * attn[qi*32 + ki];
  }
  #pragma unroll
  for (int off = 32; off > 0; off >>= 1) sum += __shfl_down(sum, off, 64);
  if (l == 0) red[w] = sum;
  __syncthreads();
  if (t == 0) out[b] = red[0] + red[1] + red[2] + red[3] + bfc[0];
}

// ---------------- host ----------------
extern "C" void kernel_launch(void* const* d_in, const int* in_sizes, int n_in,
                              void* d_out, int out_size, void* d_ws, size_t ws_size,
                              hipStream_t stream) {
  const float* x   = (const float*)d_in[0];
  const float* pe  = (const float*)d_in[1];
  const float* Wq  = (const float*)d_in[2];
  const float* bq  = (const float*)d_in[3];
  const float* Wk  = (const float*)d_in[4];
  const float* bk  = (const float*)d_in[5];
  const float* Wv  = (const float*)d_in[6];
  const float* bv  = (const float*)d_in[7];
  const float* Wfc = (const float*)d_in[8];
  const float* bfc = (const float*)d_in[9];
  float* out = (float*)d_out;
  (void)in_sizes; (void)n_in; (void)out_size; (void)ws_size;

  char* ws = (char*)d_ws;
  size_t off = 0;
  auto alloc = [&](size_t bytes) -> void* {
    void* p = ws + off;
    off += (bytes + 255) & ~(size_t)255;
    return p;
  };
  ushort_t* xb       = (ushort_t*)alloc((size_t)M_TOT * KDIM * 2);   //  64 MiB
  ushort_t* Wall     = (ushort_t*)alloc((size_t)N2 * KDIM * 2);      //   8 MiB
  float*    bias_all = (float*)   alloc((size_t)SSEQ * N2 * 4);      // 512 KiB
  float*    Wpv      = (float*)   alloc((size_t)SSEQ * D2 * 4);      // 256 KiB
  ushort_t* Wpvb     = (ushort_t*)alloc((size_t)SSEQ * KDIM * 2);    //  64 KiB
  float*    biasp    = (float*)   alloc((size_t)SSEQ * SSEQ * 4);    //   4 KiB
  ushort_t* qkv      = (ushort_t*)alloc((size_t)M_TOT * N2 * 2);     // 256 MiB

  k_cast_x <<<dim3(M_TOT*KDIM/8/256), dim3(256), 0, stream>>>(x, xb);
  k_cast_w <<<dim3(N2*KDIM/8/256),    dim3(256), 0, stream>>>(Wq, Wk, Wall);
  k_wpv    <<<dim3(32),               dim3(256), 0, stream>>>(Wv, Wfc, Wpv, Wpvb);
  k_biasp  <<<dim3(4),                dim3(256), 0, stream>>>(pe, Wpv, bv, Wfc, biasp);
  k_bias   <<<dim3(N2/8),             dim3(256), 0, stream>>>(pe, Wq, bq, Wk, bk, bias_all);
  k_gemm   <<<dim3(M_TOT/256, N2/256), dim3(512), 0, stream>>>(xb, Wall, bias_all, qkv);
  k_attn   <<<dim3(NBATCH),           dim3(256), 0, stream>>>(qkv, xb, Wpvb, biasp, bfc, out);
}

// Round 9
// 558.785 us; speedup vs baseline: 1.6044x; 1.6044x over previous
//
#include <hip/hip_runtime.h>

typedef unsigned short ushort_t;
typedef __attribute__((ext_vector_type(8))) short short8;
typedef __attribute__((ext_vector_type(8))) unsigned short ushort8;
typedef __attribute__((ext_vector_type(4))) float floatx4;

#define KDIM 1024
#define D2   2048
#define NB   1024
#define N2   4096

__device__ __forceinline__ ushort_t f2bf(float f){
  unsigned int u = __builtin_bit_cast(unsigned int, f);
  u += 0x7fffu + ((u >> 16) & 1u);           // RNE
  return (ushort_t)(u >> 16);
}
__device__ __forceinline__ float bf2f(ushort_t u){
  return __builtin_bit_cast(float, ((unsigned)u) << 16);
}
__device__ __forceinline__ void gld16(const void* g, void* l){
  __builtin_amdgcn_global_load_lds((__attribute__((address_space(1))) void*)g,
                                   (__attribute__((address_space(3))) void*)l,
                                   16, 0, 0);
}

// ---------------- prep kernels ----------------

__global__ void k_cast_x(const float* __restrict__ x, ushort_t* __restrict__ xb){
  size_t i = (size_t)blockIdx.x * 256 + threadIdx.x;
  const float4* s = (const float4*)x;
  float4 a = s[2*i], b = s[2*i+1];
  ushort8 o;
  o[0]=f2bf(a.x); o[1]=f2bf(a.y); o[2]=f2bf(a.z); o[3]=f2bf(a.w);
  o[4]=f2bf(b.x); o[5]=f2bf(b.y); o[6]=f2bf(b.z); o[7]=f2bf(b.w);
  *(ushort8*)(xb + 8*i) = o;
}

// WqT[j][n] = Wq[n][j] (bf16), j<1024, n<2048; z selects Wq/Wk
__global__ void k_trans(const float* __restrict__ Wq, const float* __restrict__ Wk,
                        ushort_t* __restrict__ WqT, ushort_t* __restrict__ WkT){
  __shared__ float tile[64][65];
  const float* in = blockIdx.z ? Wk : Wq;
  ushort_t* out = blockIdx.z ? WkT : WqT;
  int j0 = blockIdx.x * 64;      // 16 blocks
  int n0 = blockIdx.y * 64;      // 32 blocks
  int t = threadIdx.x;
  int rc = t >> 4, cc = (t & 15) * 4;
  #pragma unroll
  for (int p = 0; p < 4; ++p){
    int n = p*16 + rc;
    float4 v = *(const float4*)(in + (size_t)(n0+n)*D2 + j0 + cc);
    tile[n][cc] = v.x; tile[n][cc+1] = v.y; tile[n][cc+2] = v.z; tile[n][cc+3] = v.w;
  }
  __syncthreads();
  #pragma unroll
  for (int p = 0; p < 2; ++p){
    int u = p*256 + t;
    int j = u >> 3, sg = (u & 7)*8;
    ushort8 o;
    #pragma unroll
    for (int e = 0; e < 8; ++e) o[e] = f2bf(tile[sg+e][j]);
    *(ushort8*)(out + (size_t)(j0+j)*D2 + n0 + sg) = o;
  }
}

// bias_all[s][p*2048+n] = b_p[n] + pe[s]·W_p[n][1024:]  (fp32), p in {q,k}
__global__ void k_bias(const float* __restrict__ pe,
                       const float* __restrict__ Wq, const float* __restrict__ bq,
                       const float* __restrict__ Wk, const float* __restrict__ bk,
                       float* __restrict__ bias_all){
  int t = threadIdx.x;
  int ni = t & 7, s = t >> 3;
  int col = blockIdx.x * 8 + ni;           // 0..4095
  int p = col >> 11, n = col & 2047;
  const float* W  = (p==0) ? Wq : Wk;
  const float* bb = (p==0) ? bq : bk;
  const float4* w4 = (const float4*)(W + (size_t)n*D2 + 1024);
  const float4* p4 = (const float4*)(pe + (size_t)s*1024);
  float acc = 0.f;
  #pragma unroll 4
  for (int j = 0; j < 256; ++j){
    float4 w = w4[j], q = p4[j];
    acc += w.x*q.x + w.y*q.y + w.z*q.z + w.w*q.w;
  }
  bias_all[(size_t)s*N2 + col] = acc + bb[n];
}

// Mt[j2][j1] = sum_n Wk[n][j2] Wq[n][j1]; split-K: grid (8,8,4), 128^2 tile, K-chunk 512
__global__ __launch_bounds__(256) void k_mt(const ushort_t* __restrict__ WkT,
                                            const ushort_t* __restrict__ WqT,
                                            float* __restrict__ Mpart){
  __shared__ alignas(16) ushort_t sA[128*64], sB[128*64];
  const int m0 = blockIdx.x*128, n0 = blockIdx.y*128;
  const size_t kb = (size_t)blockIdx.z * 512;
  const int t = threadIdx.x, w = t >> 6, l = t & 63;
  const int wr = w >> 1, wc = w & 1;
  const int lr = l & 15, lg = l >> 4;
  floatx4 acc[4][4] = {};
  for (int kt = 0; kt < 512; kt += 64){
    #pragma unroll
    for (int j = 0; j < 4; ++j){
      int p = j*256 + t;
      int row = p >> 3, c = (p & 7) ^ (row & 7);
      gld16(WkT + (size_t)(m0+row)*D2 + kb + kt + c*8, &sA[(size_t)(j*256 + w*64)*8]);
      gld16(WqT + (size_t)(n0+row)*D2 + kb + kt + c*8, &sB[(size_t)(j*256 + w*64)*8]);
    }
    __syncthreads();
    #pragma unroll
    for (int ks = 0; ks < 2; ++ks){
      short8 af[4], bfv[4];
      #pragma unroll
      for (int mi = 0; mi < 4; ++mi){
        int ch = (ks*4 + lg) ^ (lr & 7);
        af[mi] = *(const short8*)&sA[(size_t)((wr*64 + mi*16 + lr)*8 + ch)*8];
      }
      #pragma unroll
      for (int ni = 0; ni < 4; ++ni){
        int ch = (ks*4 + lg) ^ (lr & 7);
        bfv[ni] = *(const short8*)&sB[(size_t)((wc*64 + ni*16 + lr)*8 + ch)*8];
      }
      #pragma unroll
      for (int mi = 0; mi < 4; ++mi)
        #pragma unroll
        for (int ni = 0; ni < 4; ++ni)
          acc[mi][ni] = __builtin_amdgcn_mfma_f32_16x16x32_bf16(af[mi], bfv[ni], acc[mi][ni], 0, 0, 0);
    }
    __syncthreads();
  }
  float* o = Mpart + (size_t)blockIdx.z*1024*1024;
  #pragma unroll
  for (int mi = 0; mi < 4; ++mi)
    #pragma unroll
    for (int ni = 0; ni < 4; ++ni)
      #pragma unroll
      for (int r = 0; r < 4; ++r)
        o[(size_t)(m0 + mi*16 + wr*64 + lg*4 + r)*1024 + n0 + wc*64 + ni*16 + lr] = acc[mi][ni][r];
}

__global__ void k_mtred(const float* __restrict__ Mp, ushort_t* __restrict__ Mt){
  size_t i = ((size_t)blockIdx.x*256 + threadIdx.x)*8;
  ushort8 o;
  #pragma unroll
  for (int e = 0; e < 8; ++e){
    float s = Mp[i+e] + Mp[1048576+i+e] + Mp[2097152+i+e] + Mp[3145728+i+e];
    o[e] = f2bf(s);
  }
  *(ushort8*)(Mt + i) = o;
}

// Wpv partials: part[dt][qi][j] = sum_{d in chunk} Wfc[qi][d] Wv[d][j]
__global__ void k_wpv1(const float* __restrict__ Wv, const float* __restrict__ Wfc,
                       float* __restrict__ part){
  int j = blockIdx.x*64 + (threadIdx.x & 63);
  int qg = threadIdx.x >> 6;
  int d0 = blockIdx.y * 128;
  float acc[8] = {};
  for (int d = d0; d < d0+128; ++d){
    float wv = Wv[(size_t)d*D2 + j];
    #pragma unroll
    for (int u = 0; u < 8; ++u)
      acc[u] += wv * Wfc[(size_t)(qg*8+u)*D2 + d];
  }
  #pragma unroll
  for (int u = 0; u < 8; ++u)
    part[((size_t)blockIdx.y*32 + qg*8+u)*D2 + j] = acc[u];
}

__global__ void k_wpv2(const float* __restrict__ part, float* __restrict__ Wpv,
                       ushort_t* __restrict__ Wpvb){
  int idx = blockIdx.x*256 + threadIdx.x;   // 0..65535
  int qi = idx >> 11, j = idx & 2047;
  float s = 0.f;
  #pragma unroll
  for (int c = 0; c < 16; ++c)
    s += part[((size_t)c*32 + qi)*D2 + j];
  Wpv[(size_t)qi*D2 + j] = s;
  if (j < 1024) Wpvb[(size_t)qi*KDIM + j] = f2bf(s);
}

// U[ki][j] = sum_n WqT[j][n] biask[ki][n]; V[qi][j] = sum_n WkT[j][n] biasq[qi][n];
// W4[qi][ki] = biasq[qi]·biask[ki]; biasp[s][qi] = pe[s]·Wpv_r[qi] + bv·Wfc_r[qi]
__global__ void k_tab(const ushort_t* __restrict__ WqT, const ushort_t* __restrict__ WkT,
                      const float* __restrict__ bias_all,
                      const float* __restrict__ pe, const float* __restrict__ Wpv,
                      const float* __restrict__ bv, const float* __restrict__ Wfc,
                      ushort_t* __restrict__ U, ushort_t* __restrict__ V,
                      float* __restrict__ W4, float* __restrict__ biasp){
  int bid = blockIdx.x, t = threadIdx.x;
  if (bid < 256){
    bool isU = bid < 128;
    int i = (isU ? bid : bid-128)*256 + t;
    int s = i >> 10, j = i & 1023;
    const ushort_t* wt = (isU ? WqT : WkT) + (size_t)j*D2;
    const float* bias = bias_all + (size_t)s*N2 + (isU ? D2 : 0);
    float acc = 0.f;
    for (int n8 = 0; n8 < 256; ++n8){
      short8 wv = *(const short8*)(wt + n8*8);
      const float* bp = bias + n8*8;
      #pragma unroll
      for (int e = 0; e < 8; ++e)
        acc += bf2f((ushort_t)wv[e]) * bp[e];
    }
    (isU ? U : V)[(size_t)s*KDIM + j] = f2bf(acc);
  } else if (bid < 260){
    int i = (bid-256)*256 + t;
    int qi = i >> 5, ki = i & 31;
    const float4* a4 = (const float4*)(bias_all + (size_t)qi*N2);
    const float4* b4 = (const float4*)(bias_all + (size_t)ki*N2 + D2);
    float acc = 0.f;
    #pragma unroll 4
    for (int n = 0; n < 512; ++n){
      float4 a = a4[n], b = b4[n];
      acc += a.x*b.x + a.y*b.y + a.z*b.z + a.w*b.w;
    }
    W4[i] = acc;
  } else {
    int i = (bid-260)*256 + t;
    int s = i >> 5, qi = i & 31;
    const float4* p4 = (const float4*)(pe + (size_t)s*KDIM);
    const float4* w4 = (const float4*)(Wpv + (size_t)qi*D2 + 1024);
    float acc = 0.f;
    #pragma unroll 4
    for (int jj = 0; jj < 256; ++jj){
      float4 a = p4[jj], b = w4[jj];
      acc += a.x*b.x + a.y*b.y + a.z*b.z + a.w*b.w;
    }
    const float4* b4 = (const float4*)bv;
    const float4* f4 = (const float4*)(Wfc + (size_t)qi*D2);
    #pragma unroll 4
    for (int dd = 0; dd < 512; ++dd){
      float4 a = b4[dd], b = f4[dd];
      acc += a.x*b.x + a.y*b.y + a.z*b.z + a.w*b.w;
    }
    biasp[i] = acc;
  }
}

// ---------------- fused per-batch kernel ----------------
// logits = (Y@x^T + x@U^T + (x@V^T)^T + W4)/sqrt(2048), Y = x@Mt^T;
// softmax over qi; P[ki][qi] = x@Wpvb^T + biasp; out[b] = sum attn*P + bfc
// LDS layout (143392 B total; 160 KiB HW limit):
//   [0,65536)       xs  -> reused as p1 [0,32768) + p3 [32768,65536) after sync#1
//   [65536,131072)  ys (8 waves x 8192) -> pp [65536,98304) reused after sync#1
//   [131072,135168) aR  [135168,139264) l3  [139264,143360) pf  [143360,143392) red
__global__ __launch_bounds__(512, 1) void k_fuse(
    const ushort_t* __restrict__ xb, const ushort_t* __restrict__ Mt,
    const ushort_t* __restrict__ U, const ushort_t* __restrict__ V,
    const ushort_t* __restrict__ Wpvb, const float* __restrict__ W4,
    const float* __restrict__ biasp, const float* __restrict__ bfc,
    float* __restrict__ out){
  __shared__ alignas(16) char smem[143392];
  const int b = blockIdx.x;
  const int t = threadIdx.x, w = t >> 6, l = t & 63;
  const int lr = l & 15, lg = l >> 4;
  ushort_t* xs = (ushort_t*)smem;                      // [32 rows][128 ch][8], swizzled
  ushort_t* ys = (ushort_t*)(smem + 65536 + w*8192);   // wave-private [32][16 ch][8]
  float* p1 = (float*)smem;                            // partials (reuse after sync#1)
  float* p3 = (float*)(smem + 32768);
  float* pp = (float*)(smem + 65536);
  float* aR = (float*)(smem + 131072);
  float* l3 = (float*)(smem + 135168);
  float* pf = (float*)(smem + 139264);
  float* red = (float*)(smem + 143360);

  // stage x_b (swizzled: low3 of chunk ^= row&7)
  const ushort_t* gx = xb + (size_t)b*32*KDIM;
  #pragma unroll
  for (int j = 0; j < 8; ++j){
    int p = j*512 + t;
    int row = p >> 7, c7 = p & 127;
    int c = (c7 & ~7) | ((c7 & 7) ^ (row & 7));
    gld16(gx + (size_t)row*KDIM + c*8, xs + (size_t)(j*512 + w*64)*8);
  }
  __syncthreads();

  // ---- Y = x @ Mt^T (wave's 128 j2 rows of Mt) ----
  floatx4 accY[2][8] = {};
  short8 bc[8], bn[8], a0[2], a1[2];
  const ushort_t* mrow = Mt + (size_t)(w*128 + lr)*KDIM + lg*8;
  auto LDB = [&](short8* d, int s){
    #pragma unroll
    for (int nf = 0; nf < 8; ++nf)
      d[nf] = *(const short8*)(mrow + (size_t)nf*16*KDIM + s*32);
  };
  auto LDA = [&](short8* a, int s){
    int c = s*4 + lg;
    #pragma unroll
    for (int rf = 0; rf < 2; ++rf){
      int row = rf*16 + lr;
      int ph = (c & ~7) | ((c & 7) ^ (row & 7));
      a[rf] = *(const short8*)(xs + (size_t)(row*128 + ph)*8);
    }
  };
  auto MMY = [&](const short8* a, const short8* bb){
    #pragma unroll
    for (int rf = 0; rf < 2; ++rf)
      #pragma unroll
      for (int nf = 0; nf < 8; ++nf)
        accY[rf][nf] = __builtin_amdgcn_mfma_f32_16x16x32_bf16(a[rf], bb[nf], accY[rf][nf], 0, 0, 0);
  };
  LDB(bc, 0);
  for (int s = 0; s < 32; s += 2){
    if (s+1 < 32) LDB(bn, s+1);
    LDA(a0, s);
    MMY(a0, bc);
    if (s+2 < 32) LDB(bc, s+2);
    LDA(a1, s+1);
    MMY(a1, bn);
  }

  // issue U B-frags early
  short8 bU[2][4], bV[2][4], bP[2][4];
  #pragma unroll
  for (int bf = 0; bf < 2; ++bf)
    #pragma unroll
    for (int ks = 0; ks < 4; ++ks)
      bU[bf][ks] = *(const short8*)(U + (size_t)(bf*16+lr)*KDIM + w*128 + ks*32 + lg*8);

  // write Y -> ys (bf16, swizzled: low3 of 16 chunks ^= row&7)
  #pragma unroll
  for (int rf = 0; rf < 2; ++rf)
    #pragma unroll
    for (int nf = 0; nf < 8; ++nf)
      #pragma unroll
      for (int r = 0; r < 4; ++r){
        int row = rf*16 + lg*4 + r;
        int col = nf*16 + lr;
        int ch = col >> 3;
        int ph = (ch & 8) | ((ch & 7) ^ (row & 7));
        ys[(size_t)(row*16 + ph)*8 + (col & 7)] = f2bf(accY[rf][nf][r]);
      }
  asm volatile("s_waitcnt lgkmcnt(0)" ::: "memory");
  __builtin_amdgcn_sched_barrier(0);

  // frags: xf = x rows (k-slice w*128), ya = Y rows (own ys)
  short8 xf[2][4], ya[2][4];
  #pragma unroll
  for (int rf = 0; rf < 2; ++rf)
    #pragma unroll
    for (int ks = 0; ks < 4; ++ks){
      int row = rf*16 + lr;
      int c = w*16 + ks*4 + lg;
      int ph = (c & ~7) | ((c & 7) ^ (row & 7));
      xf[rf][ks] = *(const short8*)(xs + (size_t)(row*128 + ph)*8);
      int c2 = ks*4 + lg;
      int p2 = (c2 & 8) | ((c2 & 7) ^ (row & 7));
      ya[rf][ks] = *(const short8*)(ys + (size_t)(row*16 + p2)*8);
    }

  floatx4 aL[2][2] = {}, a3[2][2] = {}, aP[2][2] = {};
  // term1: [qi][ki] = ya x xf
  #pragma unroll
  for (int rf = 0; rf < 2; ++rf)
    #pragma unroll
    for (int bf = 0; bf < 2; ++bf)
      #pragma unroll
      for (int ks = 0; ks < 4; ++ks)
        aL[rf][bf] = __builtin_amdgcn_mfma_f32_16x16x32_bf16(ya[rf][ks], xf[bf][ks], aL[rf][bf], 0, 0, 0);
  #pragma unroll
  for (int bf = 0; bf < 2; ++bf)
    #pragma unroll
    for (int ks = 0; ks < 4; ++ks)
      bV[bf][ks] = *(const short8*)(V + (size_t)(bf*16+lr)*KDIM + w*128 + ks*32 + lg*8);
  // term2: [qi][ki] += xf x bU
  #pragma unroll
  for (int rf = 0; rf < 2; ++rf)
    #pragma unroll
    for (int bf = 0; bf < 2; ++bf)
      #pragma unroll
      for (int ks = 0; ks < 4; ++ks)
        aL[rf][bf] = __builtin_amdgcn_mfma_f32_16x16x32_bf16(xf[rf][ks], bU[bf][ks], aL[rf][bf], 0, 0, 0);
  #pragma unroll
  for (int bf = 0; bf < 2; ++bf)
    #pragma unroll
    for (int ks = 0; ks < 4; ++ks)
      bP[bf][ks] = *(const short8*)(Wpvb + (size_t)(bf*16+lr)*KDIM + w*128 + ks*32 + lg*8);
  // term3: [ki][qi] = xf x bV
  #pragma unroll
  for (int rf = 0; rf < 2; ++rf)
    #pragma unroll
    for (int bf = 0; bf < 2; ++bf)
      #pragma unroll
      for (int ks = 0; ks < 4; ++ks)
        a3[rf][bf] = __builtin_amdgcn_mfma_f32_16x16x32_bf16(xf[rf][ks], bV[bf][ks], a3[rf][bf], 0, 0, 0);
  // P: [ki][qi] = xf x bP
  #pragma unroll
  for (int rf = 0; rf < 2; ++rf)
    #pragma unroll
    for (int bf = 0; bf < 2; ++bf)
      #pragma unroll
      for (int ks = 0; ks < 4; ++ks)
        aP[rf][bf] = __builtin_amdgcn_mfma_f32_16x16x32_bf16(xf[rf][ks], bP[bf][ks], aP[rf][bf], 0, 0, 0);

  __syncthreads();   // sync#1: everyone done reading xs/ys
  // write partials (C/D: col=lr, row=lg*4+r)
  #pragma unroll
  for (int rf = 0; rf < 2; ++rf)
    #pragma unroll
    for (int bf = 0; bf < 2; ++bf)
      #pragma unroll
      for (int r = 0; r < 4; ++r){
        int row = rf*16 + lg*4 + r, col = bf*16 + lr;
        p1[w*1024 + row*32 + col] = aL[rf][bf][r];
        p3[w*1024 + row*32 + col] = a3[rf][bf][r];
        pp[w*1024 + row*32 + col] = aP[rf][bf][r];
      }
  __syncthreads();
  // reduce 8 waves
  #pragma unroll
  for (int h = 0; h < 2; ++h){
    int idx = h*512 + t;
    float s1 = 0.f, s3 = 0.f, sp = 0.f;
    #pragma unroll
    for (int ww = 0; ww < 8; ++ww){
      s1 += p1[ww*1024 + idx];
      s3 += p3[ww*1024 + idx];
      sp += pp[ww*1024 + idx];
    }
    aR[idx] = s1; l3[idx] = s3; pf[idx] = sp;
  }
  __syncthreads();
  // softmax over qi per column ki (t<32)
  if (t < 32){
    int ki = t;
    float lgv[32];
    float mx = -1e30f;
    #pragma unroll
    for (int qi = 0; qi < 32; ++qi){
      float v = (aR[qi*32+ki] + l3[ki*32+qi] + W4[qi*32+ki]) * 0.022097086912079608f;
      lgv[qi] = v; mx = fmaxf(mx, v);
    }
    float sm = 0.f;
    #pragma unroll
    for (int qi = 0; qi < 32; ++qi){ float e = __expf(lgv[qi]-mx); lgv[qi] = e; sm += e; }
    float inv = 1.f/sm;
    #pragma unroll
    for (int qi = 0; qi < 32; ++qi) aR[qi*32+ki] = lgv[qi]*inv;
  }
  __syncthreads();
  // out[b] = sum attn[qi][ki]*(P[ki][qi]+biasp[ki][qi]) + bfc
  float sum = 0.f;
  #pragma unroll
  for (int h = 0; h < 2; ++h){
    int idx = h*512 + t;
    int qi = idx >> 5, ki = idx & 31;
    sum += aR[qi*32+ki] * (pf[ki*32+qi] + biasp[ki*32+qi]);
  }
  #pragma unroll
  for (int off = 32; off > 0; off >>= 1) sum += __shfl_down(sum, off, 64);
  if (l == 0) red[w] = sum;
  __syncthreads();
  if (t == 0){
    float s = bfc[0];
    #pragma unroll
    for (int ww = 0; ww < 8; ++ww) s += red[ww];
    out[b] = s;
  }
}

// ---------------- host ----------------
extern "C" void kernel_launch(void* const* d_in, const int* in_sizes, int n_in,
                              void* d_out, int out_size, void* d_ws, size_t ws_size,
                              hipStream_t stream) {
  const float* x   = (const float*)d_in[0];
  const float* pe  = (const float*)d_in[1];
  const float* Wq  = (const float*)d_in[2];
  const float* bq  = (const float*)d_in[3];
  const float* Wk  = (const float*)d_in[4];
  const float* bk  = (const float*)d_in[5];
  const float* Wv  = (const float*)d_in[6];
  const float* bv  = (const float*)d_in[7];
  const float* Wfc = (const float*)d_in[8];
  const float* bfc = (const float*)d_in[9];
  float* out = (float*)d_out;
  (void)in_sizes; (void)n_in; (void)out_size; (void)ws_size;

  char* ws = (char*)d_ws;
  size_t off = 0;
  auto alloc = [&](size_t bytes) -> void* {
    void* p = ws + off;
    off += (bytes + 255) & ~(size_t)255;
    return p;
  };
  ushort_t* xb       = (ushort_t*)alloc((size_t)NB*32 * KDIM * 2);   //  64 MiB
  ushort_t* WqT      = (ushort_t*)alloc((size_t)KDIM * D2 * 2);      //   4 MiB
  ushort_t* WkT      = (ushort_t*)alloc((size_t)KDIM * D2 * 2);      //   4 MiB
  float*    Mpart    = (float*)   alloc((size_t)4 * KDIM * KDIM * 4);// 16 MiB
  ushort_t* Mt       = (ushort_t*)alloc((size_t)KDIM * KDIM * 2);    //   2 MiB
  float*    wpv_part = (float*)   alloc((size_t)16 * 32 * D2 * 4);   //   4 MiB
  float*    Wpv      = (float*)   alloc((size_t)32 * D2 * 4);        // 256 KiB
  ushort_t* Wpvb     = (ushort_t*)alloc((size_t)32 * KDIM * 2);      //  64 KiB
  float*    bias_all = (float*)   alloc((size_t)32 * N2 * 4);        // 512 KiB
  ushort_t* U        = (ushort_t*)alloc((size_t)32 * KDIM * 2);      //  64 KiB
  ushort_t* V        = (ushort_t*)alloc((size_t)32 * KDIM * 2);      //  64 KiB
  float*    W4       = (float*)   alloc((size_t)32 * 32 * 4);        //   4 KiB
  float*    biasp    = (float*)   alloc((size_t)32 * 32 * 4);        //   4 KiB

  k_cast_x <<<dim3(16384),      dim3(256), 0, stream>>>(x, xb);
  k_trans  <<<dim3(16, 32, 2),  dim3(256), 0, stream>>>(Wq, Wk, WqT, WkT);
  k_bias   <<<dim3(512),        dim3(256), 0, stream>>>(pe, Wq, bq, Wk, bk, bias_all);
  k_mt     <<<dim3(8, 8, 4),    dim3(256), 0, stream>>>(WkT, WqT, Mpart);
  k_mtred  <<<dim3(512),        dim3(256), 0, stream>>>(Mpart, Mt);
  k_wpv1   <<<dim3(32, 16),     dim3(256), 0, stream>>>(Wv, Wfc, wpv_part);
  k_wpv2   <<<dim3(256),        dim3(256), 0, stream>>>(wpv_part, Wpv, Wpvb);
  k_tab    <<<dim3(264),        dim3(256), 0, stream>>>(WqT, WkT, bias_all, pe, Wpv, bv, Wfc, U, V, W4, biasp);
  k_fuse   <<<dim3(NB),         dim3(512), 0, stream>>>(xb, Mt, U, V, Wpvb, W4, biasp, bfc, out);
}